// Round 6
// baseline (600.950 us; speedup 1.0000x reference)
//
#include <hip/hip_runtime.h>
#include <math.h>

#define B_ 2
#define C_ 36
#define H_ 512
#define W_ 512
#define K_ 9
#define HW_ (H_ * W_)
#define HW4_ (HW_ / 4)
#define ROWF4 (W_ * C_ / 4)  // float4 pitch of one image row in featT = 4608

// ---------------------------------------------------------------------------
// Transpose features [B,C,H,W] -> [B,H,W,C], v3.
// The ~120us total-minus-eval gap every round == transpose at 1.25 TB/s.
// v2's read side was scalar 4B/lane (256 B per wave-instr).  v3 reads float4:
// one wave covers a 128-px strip for 2 channels per instr (512 B/c visit),
// 4x fewer, 4x fatter VMEM ops.  128-px strips cut LDS to 18.9 KB -> 8
// blocks/CU and double the block count (4096) for better HBM stream overlap.
// Write side unchanged: fully-coalesced contiguous float4 runs.
// ---------------------------------------------------------------------------
__global__ __launch_bounds__(256) void transpose_kernel3(const float* __restrict__ in,
                                                         float* __restrict__ out) {
  __shared__ float tile[128][37];  // 18.9 KB
  int blk = blockIdx.x;            // ((b*H + h) << 2) | strip
  int strip = blk & 3;
  int h = (blk >> 2) & (H_ - 1);
  int b = blk >> 11;
  int w0 = strip << 7;
  int tid = threadIdx.x;

  const float4* src4 = reinterpret_cast<const float4*>(in) +
                       ((size_t)b * C_ * HW_ + (size_t)h * W_ + w0) / 4;
#pragma unroll
  for (int it = 0; it < 5; ++it) {
    int idx = it * 256 + tid;  // 0..1151 = 36 c x 32 lanes
    if (idx < C_ * 32) {
      int c = idx >> 5;
      int l = idx & 31;
      float4 v = src4[(size_t)c * HW4_ + l];
      tile[4 * l + 0][c] = v.x;
      tile[4 * l + 1][c] = v.y;
      tile[4 * l + 2][c] = v.z;
      tile[4 * l + 3][c] = v.w;
    }
  }
  __syncthreads();
  float4* dst4 = reinterpret_cast<float4*>(out + (((size_t)b * H_ + h) * W_ + w0) * C_);
#pragma unroll
  for (int it = 0; it < 5; ++it) {
    int idx = it * 256 + tid;  // float4 index 0..1151 within the strip
    if (idx < 128 * 9) {
      int px = idx / 9;
      int qq = idx - 9 * px;
      dst4[idx] = make_float4(tile[px][4 * qq + 0], tile[px][4 * qq + 1],
                              tile[px][4 * qq + 2], tile[px][4 * qq + 3]);
    }
  }
}

// ---------------------------------------------------------------------------
// v9: identical body to v8 (K-split: 3 waves/WG, wave wv owns candidates
// {3wv..3wv+2}; F in LDS; no spill), with __launch_bounds__(192, 5).
// Occupancy law measured across v4/v6/v7/v8: achieved waves/CU ~= 80% of
// (4 x launch_bounds 2nd arg) — the waves-per-EU declaration acts as a cap.
// v8's (192,2) capped us at ~5.4 waves/CU (17%) despite LDS allowing 18 and
// VGPR (88) allowing 20.  (192,5): VGPR cap 512/5=102 >= 88 natural -> same
// codegen, occupancy cap 20, LDS binds at 18 waves/CU.  Pixel front stays
// 6 WG/CU x 64 px = 12K px/XCD == v4's proven L2-safe band (FETCH 78 MB).
// ---------------------------------------------------------------------------
__global__ __launch_bounds__(192, 5) void eval_kernel_ks(const float* __restrict__ feat,
                                                         const float* __restrict__ offx,
                                                         const float* __restrict__ offy,
                                                         float* __restrict__ out) {
  __shared__ __align__(16) float scratch[3][32 * 36];  // per-wave gather scratch; reused for merge
  __shared__ __align__(16) float4 w_lds[3][64];        // per-wave bilinear weights
  __shared__ int a_lds[3][64];                         // per-wave row0-run float4 base index
  __shared__ float F_lds[C_][64];                      // center features, channel-major (9.2 KB)

  int tid = threadIdx.x;
  int wv = tid >> 6;  // wave 0..2 -> k-set {3wv, 3wv+1, 3wv+2}
  int ln = tid & 63;

  int blk = blockIdx.x;
  int region = blk & 7;  // XCD round-robin residue -> fixed 256x256 region
  int slot = blk >> 3;   // 0..1023 within region
  int b = region >> 2;
  int qd = region & 3;
  int qy = (qd >> 1) << 8;
  int qx = (qd & 1) << 8;
  int tr = slot >> 5;  // 0..31
  int tc = slot & 31;
  if (tr & 1) tc = 31 - tc;  // serpentine: consecutive blocks share halo
  int h = qy + tr * 8 + (ln >> 3);
  int w = qx + tc * 8 + (ln & 7);
  int ph = h * W_ + w;
  int p = b * HW_ + ph;

  const float4* feat4 = reinterpret_cast<const float4*>(feat);

  // this wave's 3 candidates' offsets for my pixel
  const float* oxb = offx + (size_t)b * K_ * HW_ + ph;
  const float* oyb = offy + (size_t)b * K_ * HW_ + ph;
  float oxv[3], oyv[3];
#pragma unroll
  for (int j = 0; j < 3; ++j) {
    oxv[j] = oxb[(3 * wv + j) * HW_];
    oyv[j] = oyb[(3 * wv + j) * HW_];
  }

  // own pixel's center features -> LDS, cooperatively: wave wv loads channel
  // quads 3wv..3wv+2 of its pixel (disjoint (c,ln) cells, no races).
  {
    const float4* myF = feat4 + (size_t)p * 9;
#pragma unroll
    for (int i = 0; i < 3; ++i) {
      int ii = 3 * wv + i;
      float4 v = myF[ii];
      F_lds[4 * ii + 0][ln] = v.x;
      F_lds[4 * ii + 1][ln] = v.y;
      F_lds[4 * ii + 2][ln] = v.z;
      F_lds[4 * ii + 3][ln] = v.w;
    }
  }
  __syncthreads();

  int g = ln / 9;      // gather group 0..7 (g==7 -> lane 63, stores suppressed)
  int q = ln - 9 * g;  // channel-quad within task

  float lx = (float)w;
  float ly = (float)h;

  float M = -INFINITY, den = 0.f, axs = 0.f, ays = 0.f;

  float* myScr = scratch[wv];

#pragma unroll 1
  for (int j = 0; j < 3; ++j) {
    // --- meta for my task (candidate k = 3*wv + j) ---
    float ox = oxv[j];
    float oy = oyv[j];
    float rx = fminf(fmaxf(lx + ox, 0.0f), 511.0f);
    float ry = fminf(fmaxf(ly + oy, 0.0f), 511.0f);
    float gx = (rx - 255.5f) / 255.5f;
    float gy = (ry - 255.5f) / 255.5f;
    float px = (gx + 1.0f) * 0.5f * 511.0f;
    float py = (gy + 1.0f) * 0.5f * 511.0f;
    int x0 = (int)floorf(px); x0 = (x0 > 510) ? 510 : x0;
    int y0 = (int)floorf(py); y0 = (y0 > 510) ? 510 : y0;
    float wx = px - (float)x0;
    float wy = py - (float)y0;
    w_lds[wv][ln] = make_float4((1.0f - wx) * (1.0f - wy), wx * (1.0f - wy),
                                (1.0f - wx) * wy, wx * wy);
    a_lds[wv][ln] = ((b * H_ + y0) * W_ + x0) * 9;  // float4 index of row0 run
    // no barrier: producer and consumers are the SAME wave; DS ops are
    // in-order per wave.

    float4 L[5][4];
    // --- issue phase A (tasks 0..31): 20 coalesced 9-lane-run loads ---
#pragma unroll
    for (int r = 0; r < 5; ++r) {
      int tt = 7 * r + g;
      int t = (tt > 31) ? 31 : tt;
      const float4* r0 = feat4 + a_lds[wv][t];
      L[r][0] = r0[q];
      L[r][1] = r0[9 + q];
      L[r][2] = r0[ROWF4 + q];
      L[r][3] = r0[ROWF4 + 9 + q];
    }
    // --- consume phase A ---
#pragma unroll
    for (int r = 0; r < 5; ++r) {
      int tt = 7 * r + g;
      int t = (tt > 31) ? 31 : tt;
      float4 W4 = w_lds[wv][t];
      float4 v00 = L[r][0], v01 = L[r][1], v10 = L[r][2], v11 = L[r][3];
      float4 a4;
      a4.x = W4.x * v00.x + W4.y * v01.x + W4.z * v10.x + W4.w * v11.x;
      a4.y = W4.x * v00.y + W4.y * v01.y + W4.z * v10.y + W4.w * v11.y;
      a4.z = W4.x * v00.z + W4.y * v01.z + W4.z * v10.z + W4.w * v11.z;
      a4.w = W4.x * v00.w + W4.y * v01.w + W4.z * v10.w + W4.w * v11.w;
      if (tt < 32 && ln < 63) {
        *reinterpret_cast<float4*>(&myScr[t * 36 + 4 * q]) = a4;
      }
    }
    // --- issue phase B (tasks 32..63) BEFORE the phase-A reduce ---
#pragma unroll
    for (int r = 0; r < 5; ++r) {
      int tt = 32 + 7 * r + g;
      int t = (tt > 63) ? 63 : tt;
      const float4* r0 = feat4 + a_lds[wv][t];
      L[r][0] = r0[q];
      L[r][1] = r0[9 + q];
      L[r][2] = r0[ROWF4 + q];
      L[r][3] = r0[ROWF4 + 9 + q];
    }
    // --- phase-A owner reduce + softmax (lanes 0..31 own pixels 0..31) ---
    if (ln < 32) {
      float D[9] = {0.f, 0.f, 0.f, 0.f, 0.f, 0.f, 0.f, 0.f, 0.f};
      const float4* sc = reinterpret_cast<const float4*>(&myScr[ln * 36]);
#pragma unroll
      for (int q2 = 0; q2 < 9; ++q2) {
        float4 a4 = sc[q2];
        float av[4] = {a4.x, a4.y, a4.z, a4.w};
        int ga = q2 / 3;
        int f0 = 4 * (q2 % 3);
#pragma unroll
        for (int jj = 0; jj < 4; ++jj) {
          D[ga]     += fabsf(F_lds[f0 + jj][ln]      - av[jj]);
          D[3 + ga] += fabsf(F_lds[12 + f0 + jj][ln] - av[jj]);
          D[6 + ga] += fabsf(F_lds[24 + f0 + jj][ln] - av[jj]);
        }
      }
      float mn = D[0];
#pragma unroll
      for (int jj = 1; jj < 9; ++jj) mn = fminf(mn, D[jj]);
      float xk = -(mn / 12.0f) * 1000.0f;
      float nm = fmaxf(M, xk);
      float scl = expf(M - nm);
      float ek = expf(xk - nm);
      den = den * scl + ek;
      axs = axs * scl + ox * ek;
      ays = ays * scl + oy * ek;
      M = nm;
    }
    // --- consume phase B (in-order DS: these writes follow the reads above) ---
#pragma unroll
    for (int r = 0; r < 5; ++r) {
      int tt = 32 + 7 * r + g;
      int t = (tt > 63) ? 63 : tt;
      float4 W4 = w_lds[wv][t];
      float4 v00 = L[r][0], v01 = L[r][1], v10 = L[r][2], v11 = L[r][3];
      float4 a4;
      a4.x = W4.x * v00.x + W4.y * v01.x + W4.z * v10.x + W4.w * v11.x;
      a4.y = W4.x * v00.y + W4.y * v01.y + W4.z * v10.y + W4.w * v11.y;
      a4.z = W4.x * v00.z + W4.y * v01.z + W4.z * v10.z + W4.w * v11.z;
      a4.w = W4.x * v00.w + W4.y * v01.w + W4.z * v10.w + W4.w * v11.w;
      if (tt < 64 && ln < 63) {
        *reinterpret_cast<float4*>(&myScr[(t - 32) * 36 + 4 * q]) = a4;
      }
    }
    // --- phase-B owner reduce + softmax (lanes 32..63 own pixels 32..63) ---
    if (ln >= 32) {
      float D[9] = {0.f, 0.f, 0.f, 0.f, 0.f, 0.f, 0.f, 0.f, 0.f};
      const float4* sc = reinterpret_cast<const float4*>(&myScr[(ln - 32) * 36]);
#pragma unroll
      for (int q2 = 0; q2 < 9; ++q2) {
        float4 a4 = sc[q2];
        float av[4] = {a4.x, a4.y, a4.z, a4.w};
        int ga = q2 / 3;
        int f0 = 4 * (q2 % 3);
#pragma unroll
        for (int jj = 0; jj < 4; ++jj) {
          D[ga]     += fabsf(F_lds[f0 + jj][ln]      - av[jj]);
          D[3 + ga] += fabsf(F_lds[12 + f0 + jj][ln] - av[jj]);
          D[6 + ga] += fabsf(F_lds[24 + f0 + jj][ln] - av[jj]);
        }
      }
      float mn = D[0];
#pragma unroll
      for (int jj = 1; jj < 9; ++jj) mn = fminf(mn, D[jj]);
      float xk = -(mn / 12.0f) * 1000.0f;
      float nm = fmaxf(M, xk);
      float scl = expf(M - nm);
      float ek = expf(xk - nm);
      den = den * scl + ek;
      axs = axs * scl + ox * ek;
      ays = ays * scl + oy * ek;
      M = nm;
    }
  }

  // --- merge the 3 waves' partial softmax states (each lane owns pixel ln) ---
  *reinterpret_cast<float4*>(&myScr[ln * 4]) = make_float4(M, den, axs, ays);
  __syncthreads();
  if (wv == 0) {
    float4 s0 = *reinterpret_cast<const float4*>(&scratch[0][ln * 4]);
    float4 s1 = *reinterpret_cast<const float4*>(&scratch[1][ln * 4]);
    float4 s2 = *reinterpret_cast<const float4*>(&scratch[2][ln * 4]);
    float nm = fmaxf(s0.x, fmaxf(s1.x, s2.x));
    float e0 = expf(s0.x - nm);
    float e1 = expf(s1.x - nm);
    float e2 = expf(s2.x - nm);
    float dent = s0.y * e0 + s1.y * e1 + s2.y * e2;
    float ax = s0.z * e0 + s1.z * e1 + s2.z * e2;
    float ay = s0.w * e0 + s1.w * e1 + s2.w * e2;
    float resx = ax / dent;
    float resy = ay / dent;
    out[p] = fminf(fmaxf(resx + lx, 0.0f), 511.0f) - lx;
    out[B_ * HW_ + p] = fminf(fmaxf(resy + ly, 0.0f), 511.0f) - ly;
  }
}

// Fallback (no scratch): original channel-major layout, thread-per-pixel.
__global__ __launch_bounds__(256) void eval_kernel_n(const float* __restrict__ feat,
                                                     const float* __restrict__ offx,
                                                     const float* __restrict__ offy,
                                                     float* __restrict__ out) {
  int p = blockIdx.x * 256 + threadIdx.x;
  int ph = p & (HW_ - 1);
  int b = p >> 18;
  float F[C_];
  const float* fb = feat + (size_t)b * C_ * HW_ + ph;
#pragma unroll
  for (int c = 0; c < C_; ++c) F[c] = fb[(size_t)c * HW_];
  float lx = (float)(ph & (W_ - 1));
  float ly = (float)((ph >> 9) & (H_ - 1));
  const float* oxb = offx + (size_t)b * K_ * HW_ + ph;
  const float* oyb = offy + (size_t)b * K_ * HW_ + ph;
  float M = -INFINITY, den = 0.f, ax = 0.f, ay = 0.f;
#pragma unroll 1
  for (int k = 0; k < K_; ++k) {
    float ox = oxb[k * HW_];
    float oy = oyb[k * HW_];
    float rx = fminf(fmaxf(lx + ox, 0.0f), 511.0f);
    float ry = fminf(fmaxf(ly + oy, 0.0f), 511.0f);
    float gx = (rx - 255.5f) / 255.5f;
    float gy = (ry - 255.5f) / 255.5f;
    float px = (gx + 1.0f) * 0.5f * 511.0f;
    float py = (gy + 1.0f) * 0.5f * 511.0f;
    int x0 = (int)floorf(px); x0 = (x0 > 510) ? 510 : x0;
    int y0 = (int)floorf(py); y0 = (y0 > 510) ? 510 : y0;
    float wx = px - (float)x0;
    float wy = py - (float)y0;
    float w00 = (1.0f - wx) * (1.0f - wy);
    float w01 = wx * (1.0f - wy);
    float w10 = (1.0f - wx) * wy;
    float w11 = wx * wy;
    float D[9] = {0.f, 0.f, 0.f, 0.f, 0.f, 0.f, 0.f, 0.f, 0.f};
    const float* pl = feat + (size_t)b * C_ * HW_ + (size_t)y0 * W_ + x0;
#pragma unroll
    for (int c = 0; c < C_; ++c) {
      const float* q0 = pl + (size_t)c * HW_;
      float v00 = q0[0], v01 = q0[1];
      float v10 = q0[W_], v11 = q0[W_ + 1];
      float a = v00 * w00 + v01 * w01 + v10 * w10 + v11 * w11;
      int i = c % 12;
      int ga = c / 12;
      D[ga]     += fabsf(F[i]      - a);
      D[3 + ga] += fabsf(F[12 + i] - a);
      D[6 + ga] += fabsf(F[24 + i] - a);
    }
    float mn = D[0];
#pragma unroll
    for (int j = 1; j < 9; ++j) mn = fminf(mn, D[j]);
    float xk = -(mn / 12.0f) * 1000.0f;
    float nm = fmaxf(M, xk);
    float sc = expf(M - nm);
    float ek = expf(xk - nm);
    den = den * sc + ek;
    ax = ax * sc + ox * ek;
    ay = ay * sc + oy * ek;
    M = nm;
  }
  float resx = ax / den;
  float resy = ay / den;
  out[p] = fminf(fmaxf(resx + lx, 0.0f), 511.0f) - lx;
  out[B_ * HW_ + p] = fminf(fmaxf(resy + ly, 0.0f), 511.0f) - ly;
}

extern "C" void kernel_launch(void* const* d_in, const int* in_sizes, int n_in,
                              void* d_out, int out_size, void* d_ws, size_t ws_size,
                              hipStream_t stream) {
  const float* features = (const float*)d_in[0];
  const float* offset_x = (const float*)d_in[1];
  const float* offset_y = (const float*)d_in[2];
  float* out = (float*)d_out;

  const int npix = B_ * HW_;  // 524288
  const size_t need = (size_t)npix * C_ * sizeof(float);  // 75.5 MB

  if (ws_size >= need) {
    float* featT = (float*)d_ws;
    transpose_kernel3<<<B_ * H_ * 4, 256, 0, stream>>>(features, featT);
    eval_kernel_ks<<<npix / 64, 192, 0, stream>>>(featT, offset_x, offset_y, out);
  } else {
    eval_kernel_n<<<npix / 256, 256, 0, stream>>>(features, offset_x, offset_y, out);
  }
}

// Round 7
// 332.018 us; speedup vs baseline: 1.8100x; 1.8100x over previous
//
#include <hip/hip_runtime.h>
#include <math.h>

#define B_ 2
#define C_ 36
#define H_ 512
#define W_ 512
#define K_ 9
#define HW_ (H_ * W_)
#define HW4_ (HW_ / 4)
#define ROWF4 (W_ * C_ / 4)  // float4 pitch of one image row in featT = 4608

// ---------------------------------------------------------------------------
// Transpose features [B,C,H,W] -> [B,H,W,C], v3.  (unchanged from round 5)
// ---------------------------------------------------------------------------
__global__ __launch_bounds__(256) void transpose_kernel3(const float* __restrict__ in,
                                                         float* __restrict__ out) {
  __shared__ float tile[128][37];  // 18.9 KB
  int blk = blockIdx.x;            // ((b*H + h) << 2) | strip
  int strip = blk & 3;
  int h = (blk >> 2) & (H_ - 1);
  int b = blk >> 11;
  int w0 = strip << 7;
  int tid = threadIdx.x;

  const float4* src4 = reinterpret_cast<const float4*>(in) +
                       ((size_t)b * C_ * HW_ + (size_t)h * W_ + w0) / 4;
#pragma unroll
  for (int it = 0; it < 5; ++it) {
    int idx = it * 256 + tid;  // 0..1151 = 36 c x 32 lanes
    if (idx < C_ * 32) {
      int c = idx >> 5;
      int l = idx & 31;
      float4 v = src4[(size_t)c * HW4_ + l];
      tile[4 * l + 0][c] = v.x;
      tile[4 * l + 1][c] = v.y;
      tile[4 * l + 2][c] = v.z;
      tile[4 * l + 3][c] = v.w;
    }
  }
  __syncthreads();
  float4* dst4 = reinterpret_cast<float4*>(out + (((size_t)b * H_ + h) * W_ + w0) * C_);
#pragma unroll
  for (int it = 0; it < 5; ++it) {
    int idx = it * 256 + tid;  // float4 index 0..1151 within the strip
    if (idx < 128 * 9) {
      int px = idx / 9;
      int qq = idx - 9 * px;
      dst4[idx] = make_float4(tile[px][4 * qq + 0], tile[px][4 * qq + 1],
                              tile[px][4 * qq + 2], tile[px][4 * qq + 3]);
    }
  }
}

// ---------------------------------------------------------------------------
// v10: v8's body, __launch_bounds__(192) with NO waves-per-EU arg.
// Fitted compiler law (v7/v8/v9): 2nd arg clamps VGPR to ~256/arg -> any
// arg>=3 spills this ~88-VGPR body (v7: 64 VGPR/600MB spill; v9: 48 VGPR/
// 1.8GB spill), while the arg also CAPS runtime residency at ~80% of 4*arg
// waves/CU (v8: arg=2 -> 5.4 waves/CU, 17%, latency-exposed at 43cyc/VMEM).
// No arg (v6 evidence): VGPR stays natural AND the HW fills to static
// limits.  Statics here: LDS 27136 B -> 6 WGs/CU = 18 waves/CU (56%);
// VGPR 88 -> 20 waves/CU.  So expect ~18 waves/CU with v8's exact codegen:
// 3.3x the latency-hiding at zero spill.  Geometry unchanged (8x8 serpentine
// tiles, 12K-px front/XCD, FETCH ~78 MB proven in v8).
// ---------------------------------------------------------------------------
__global__ __launch_bounds__(192) void eval_kernel_ks(const float* __restrict__ feat,
                                                      const float* __restrict__ offx,
                                                      const float* __restrict__ offy,
                                                      float* __restrict__ out) {
  __shared__ __align__(16) float scratch[3][32 * 36];  // per-wave gather scratch; reused for merge
  __shared__ __align__(16) float4 w_lds[3][64];        // per-wave bilinear weights
  __shared__ int a_lds[3][64];                         // per-wave row0-run float4 base index
  __shared__ float F_lds[C_][64];                      // center features, channel-major (9.2 KB)

  int tid = threadIdx.x;
  int wv = tid >> 6;  // wave 0..2 -> k-set {3wv, 3wv+1, 3wv+2}
  int ln = tid & 63;

  int blk = blockIdx.x;
  int region = blk & 7;  // XCD round-robin residue -> fixed 256x256 region
  int slot = blk >> 3;   // 0..1023 within region
  int b = region >> 2;
  int qd = region & 3;
  int qy = (qd >> 1) << 8;
  int qx = (qd & 1) << 8;
  int tr = slot >> 5;  // 0..31
  int tc = slot & 31;
  if (tr & 1) tc = 31 - tc;  // serpentine: consecutive blocks share halo
  int h = qy + tr * 8 + (ln >> 3);
  int w = qx + tc * 8 + (ln & 7);
  int ph = h * W_ + w;
  int p = b * HW_ + ph;

  const float4* feat4 = reinterpret_cast<const float4*>(feat);

  // this wave's 3 candidates' offsets for my pixel
  const float* oxb = offx + (size_t)b * K_ * HW_ + ph;
  const float* oyb = offy + (size_t)b * K_ * HW_ + ph;
  float oxv[3], oyv[3];
#pragma unroll
  for (int j = 0; j < 3; ++j) {
    oxv[j] = oxb[(3 * wv + j) * HW_];
    oyv[j] = oyb[(3 * wv + j) * HW_];
  }

  // own pixel's center features -> LDS, cooperatively: wave wv loads channel
  // quads 3wv..3wv+2 of its pixel (disjoint (c,ln) cells, no races).
  {
    const float4* myF = feat4 + (size_t)p * 9;
#pragma unroll
    for (int i = 0; i < 3; ++i) {
      int ii = 3 * wv + i;
      float4 v = myF[ii];
      F_lds[4 * ii + 0][ln] = v.x;
      F_lds[4 * ii + 1][ln] = v.y;
      F_lds[4 * ii + 2][ln] = v.z;
      F_lds[4 * ii + 3][ln] = v.w;
    }
  }
  __syncthreads();

  int g = ln / 9;      // gather group 0..7 (g==7 -> lane 63, stores suppressed)
  int q = ln - 9 * g;  // channel-quad within task

  float lx = (float)w;
  float ly = (float)h;

  float M = -INFINITY, den = 0.f, axs = 0.f, ays = 0.f;

  float* myScr = scratch[wv];

#pragma unroll 1
  for (int j = 0; j < 3; ++j) {
    // --- meta for my task (candidate k = 3*wv + j) ---
    float ox = oxv[j];
    float oy = oyv[j];
    float rx = fminf(fmaxf(lx + ox, 0.0f), 511.0f);
    float ry = fminf(fmaxf(ly + oy, 0.0f), 511.0f);
    float gx = (rx - 255.5f) / 255.5f;
    float gy = (ry - 255.5f) / 255.5f;
    float px = (gx + 1.0f) * 0.5f * 511.0f;
    float py = (gy + 1.0f) * 0.5f * 511.0f;
    int x0 = (int)floorf(px); x0 = (x0 > 510) ? 510 : x0;
    int y0 = (int)floorf(py); y0 = (y0 > 510) ? 510 : y0;
    float wx = px - (float)x0;
    float wy = py - (float)y0;
    w_lds[wv][ln] = make_float4((1.0f - wx) * (1.0f - wy), wx * (1.0f - wy),
                                (1.0f - wx) * wy, wx * wy);
    a_lds[wv][ln] = ((b * H_ + y0) * W_ + x0) * 9;  // float4 index of row0 run
    // no barrier: producer and consumers are the SAME wave; DS ops are
    // in-order per wave.

    float4 L[5][4];
    // --- issue phase A (tasks 0..31): 20 coalesced 9-lane-run loads ---
#pragma unroll
    for (int r = 0; r < 5; ++r) {
      int tt = 7 * r + g;
      int t = (tt > 31) ? 31 : tt;
      const float4* r0 = feat4 + a_lds[wv][t];
      L[r][0] = r0[q];
      L[r][1] = r0[9 + q];
      L[r][2] = r0[ROWF4 + q];
      L[r][3] = r0[ROWF4 + 9 + q];
    }
    // --- consume phase A ---
#pragma unroll
    for (int r = 0; r < 5; ++r) {
      int tt = 7 * r + g;
      int t = (tt > 31) ? 31 : tt;
      float4 W4 = w_lds[wv][t];
      float4 v00 = L[r][0], v01 = L[r][1], v10 = L[r][2], v11 = L[r][3];
      float4 a4;
      a4.x = W4.x * v00.x + W4.y * v01.x + W4.z * v10.x + W4.w * v11.x;
      a4.y = W4.x * v00.y + W4.y * v01.y + W4.z * v10.y + W4.w * v11.y;
      a4.z = W4.x * v00.z + W4.y * v01.z + W4.z * v10.z + W4.w * v11.z;
      a4.w = W4.x * v00.w + W4.y * v01.w + W4.z * v10.w + W4.w * v11.w;
      if (tt < 32 && ln < 63) {
        *reinterpret_cast<float4*>(&myScr[t * 36 + 4 * q]) = a4;
      }
    }
    // --- issue phase B (tasks 32..63) BEFORE the phase-A reduce ---
#pragma unroll
    for (int r = 0; r < 5; ++r) {
      int tt = 32 + 7 * r + g;
      int t = (tt > 63) ? 63 : tt;
      const float4* r0 = feat4 + a_lds[wv][t];
      L[r][0] = r0[q];
      L[r][1] = r0[9 + q];
      L[r][2] = r0[ROWF4 + q];
      L[r][3] = r0[ROWF4 + 9 + q];
    }
    // --- phase-A owner reduce + softmax (lanes 0..31 own pixels 0..31) ---
    if (ln < 32) {
      float D[9] = {0.f, 0.f, 0.f, 0.f, 0.f, 0.f, 0.f, 0.f, 0.f};
      const float4* sc = reinterpret_cast<const float4*>(&myScr[ln * 36]);
#pragma unroll
      for (int q2 = 0; q2 < 9; ++q2) {
        float4 a4 = sc[q2];
        float av[4] = {a4.x, a4.y, a4.z, a4.w};
        int ga = q2 / 3;
        int f0 = 4 * (q2 % 3);
#pragma unroll
        for (int jj = 0; jj < 4; ++jj) {
          D[ga]     += fabsf(F_lds[f0 + jj][ln]      - av[jj]);
          D[3 + ga] += fabsf(F_lds[12 + f0 + jj][ln] - av[jj]);
          D[6 + ga] += fabsf(F_lds[24 + f0 + jj][ln] - av[jj]);
        }
      }
      float mn = D[0];
#pragma unroll
      for (int jj = 1; jj < 9; ++jj) mn = fminf(mn, D[jj]);
      float xk = -(mn / 12.0f) * 1000.0f;
      float nm = fmaxf(M, xk);
      float scl = expf(M - nm);
      float ek = expf(xk - nm);
      den = den * scl + ek;
      axs = axs * scl + ox * ek;
      ays = ays * scl + oy * ek;
      M = nm;
    }
    // --- consume phase B (in-order DS: these writes follow the reads above) ---
#pragma unroll
    for (int r = 0; r < 5; ++r) {
      int tt = 32 + 7 * r + g;
      int t = (tt > 63) ? 63 : tt;
      float4 W4 = w_lds[wv][t];
      float4 v00 = L[r][0], v01 = L[r][1], v10 = L[r][2], v11 = L[r][3];
      float4 a4;
      a4.x = W4.x * v00.x + W4.y * v01.x + W4.z * v10.x + W4.w * v11.x;
      a4.y = W4.x * v00.y + W4.y * v01.y + W4.z * v10.y + W4.w * v11.y;
      a4.z = W4.x * v00.z + W4.y * v01.z + W4.z * v10.z + W4.w * v11.z;
      a4.w = W4.x * v00.w + W4.y * v01.w + W4.z * v10.w + W4.w * v11.w;
      if (tt < 64 && ln < 63) {
        *reinterpret_cast<float4*>(&myScr[(t - 32) * 36 + 4 * q]) = a4;
      }
    }
    // --- phase-B owner reduce + softmax (lanes 32..63 own pixels 32..63) ---
    if (ln >= 32) {
      float D[9] = {0.f, 0.f, 0.f, 0.f, 0.f, 0.f, 0.f, 0.f, 0.f};
      const float4* sc = reinterpret_cast<const float4*>(&myScr[(ln - 32) * 36]);
#pragma unroll
      for (int q2 = 0; q2 < 9; ++q2) {
        float4 a4 = sc[q2];
        float av[4] = {a4.x, a4.y, a4.z, a4.w};
        int ga = q2 / 3;
        int f0 = 4 * (q2 % 3);
#pragma unroll
        for (int jj = 0; jj < 4; ++jj) {
          D[ga]     += fabsf(F_lds[f0 + jj][ln]      - av[jj]);
          D[3 + ga] += fabsf(F_lds[12 + f0 + jj][ln] - av[jj]);
          D[6 + ga] += fabsf(F_lds[24 + f0 + jj][ln] - av[jj]);
        }
      }
      float mn = D[0];
#pragma unroll
      for (int jj = 1; jj < 9; ++jj) mn = fminf(mn, D[jj]);
      float xk = -(mn / 12.0f) * 1000.0f;
      float nm = fmaxf(M, xk);
      float scl = expf(M - nm);
      float ek = expf(xk - nm);
      den = den * scl + ek;
      axs = axs * scl + ox * ek;
      ays = ays * scl + oy * ek;
      M = nm;
    }
  }

  // --- merge the 3 waves' partial softmax states (each lane owns pixel ln) ---
  *reinterpret_cast<float4*>(&myScr[ln * 4]) = make_float4(M, den, axs, ays);
  __syncthreads();
  if (wv == 0) {
    float4 s0 = *reinterpret_cast<const float4*>(&scratch[0][ln * 4]);
    float4 s1 = *reinterpret_cast<const float4*>(&scratch[1][ln * 4]);
    float4 s2 = *reinterpret_cast<const float4*>(&scratch[2][ln * 4]);
    float nm = fmaxf(s0.x, fmaxf(s1.x, s2.x));
    float e0 = expf(s0.x - nm);
    float e1 = expf(s1.x - nm);
    float e2 = expf(s2.x - nm);
    float dent = s0.y * e0 + s1.y * e1 + s2.y * e2;
    float ax = s0.z * e0 + s1.z * e1 + s2.z * e2;
    float ay = s0.w * e0 + s1.w * e1 + s2.w * e2;
    float resx = ax / dent;
    float resy = ay / dent;
    out[p] = fminf(fmaxf(resx + lx, 0.0f), 511.0f) - lx;
    out[B_ * HW_ + p] = fminf(fmaxf(resy + ly, 0.0f), 511.0f) - ly;
  }
}

// Fallback (no scratch): original channel-major layout, thread-per-pixel.
__global__ __launch_bounds__(256) void eval_kernel_n(const float* __restrict__ feat,
                                                     const float* __restrict__ offx,
                                                     const float* __restrict__ offy,
                                                     float* __restrict__ out) {
  int p = blockIdx.x * 256 + threadIdx.x;
  int ph = p & (HW_ - 1);
  int b = p >> 18;
  float F[C_];
  const float* fb = feat + (size_t)b * C_ * HW_ + ph;
#pragma unroll
  for (int c = 0; c < C_; ++c) F[c] = fb[(size_t)c * HW_];
  float lx = (float)(ph & (W_ - 1));
  float ly = (float)((ph >> 9) & (H_ - 1));
  const float* oxb = offx + (size_t)b * K_ * HW_ + ph;
  const float* oyb = offy + (size_t)b * K_ * HW_ + ph;
  float M = -INFINITY, den = 0.f, ax = 0.f, ay = 0.f;
#pragma unroll 1
  for (int k = 0; k < K_; ++k) {
    float ox = oxb[k * HW_];
    float oy = oyb[k * HW_];
    float rx = fminf(fmaxf(lx + ox, 0.0f), 511.0f);
    float ry = fminf(fmaxf(ly + oy, 0.0f), 511.0f);
    float gx = (rx - 255.5f) / 255.5f;
    float gy = (ry - 255.5f) / 255.5f;
    float px = (gx + 1.0f) * 0.5f * 511.0f;
    float py = (gy + 1.0f) * 0.5f * 511.0f;
    int x0 = (int)floorf(px); x0 = (x0 > 510) ? 510 : x0;
    int y0 = (int)floorf(py); y0 = (y0 > 510) ? 510 : y0;
    float wx = px - (float)x0;
    float wy = py - (float)y0;
    float w00 = (1.0f - wx) * (1.0f - wy);
    float w01 = wx * (1.0f - wy);
    float w10 = (1.0f - wx) * wy;
    float w11 = wx * wy;
    float D[9] = {0.f, 0.f, 0.f, 0.f, 0.f, 0.f, 0.f, 0.f, 0.f};
    const float* pl = feat + (size_t)b * C_ * HW_ + (size_t)y0 * W_ + x0;
#pragma unroll
    for (int c = 0; c < C_; ++c) {
      const float* q0 = pl + (size_t)c * HW_;
      float v00 = q0[0], v01 = q0[1];
      float v10 = q0[W_], v11 = q0[W_ + 1];
      float a = v00 * w00 + v01 * w01 + v10 * w10 + v11 * w11;
      int i = c % 12;
      int ga = c / 12;
      D[ga]     += fabsf(F[i]      - a);
      D[3 + ga] += fabsf(F[12 + i] - a);
      D[6 + ga] += fabsf(F[24 + i] - a);
    }
    float mn = D[0];
#pragma unroll
    for (int j = 1; j < 9; ++j) mn = fminf(mn, D[j]);
    float xk = -(mn / 12.0f) * 1000.0f;
    float nm = fmaxf(M, xk);
    float sc = expf(M - nm);
    float ek = expf(xk - nm);
    den = den * sc + ek;
    ax = ax * sc + ox * ek;
    ay = ay * sc + oy * ek;
    M = nm;
  }
  float resx = ax / den;
  float resy = ay / den;
  out[p] = fminf(fmaxf(resx + lx, 0.0f), 511.0f) - lx;
  out[B_ * HW_ + p] = fminf(fmaxf(resy + ly, 0.0f), 511.0f) - ly;
}

extern "C" void kernel_launch(void* const* d_in, const int* in_sizes, int n_in,
                              void* d_out, int out_size, void* d_ws, size_t ws_size,
                              hipStream_t stream) {
  const float* features = (const float*)d_in[0];
  const float* offset_x = (const float*)d_in[1];
  const float* offset_y = (const float*)d_in[2];
  float* out = (float*)d_out;

  const int npix = B_ * HW_;  // 524288
  const size_t need = (size_t)npix * C_ * sizeof(float);  // 75.5 MB

  if (ws_size >= need) {
    float* featT = (float*)d_ws;
    transpose_kernel3<<<B_ * H_ * 4, 256, 0, stream>>>(features, featT);
    eval_kernel_ks<<<npix / 64, 192, 0, stream>>>(featT, offset_x, offset_y, out);
  } else {
    eval_kernel_n<<<npix / 256, 256, 0, stream>>>(features, offset_x, offset_y, out);
  }
}

// Round 8
// 304.396 us; speedup vs baseline: 1.9742x; 1.0907x over previous
//
#include <hip/hip_runtime.h>
#include <math.h>

#define B_ 2
#define C_ 36
#define H_ 512
#define W_ 512
#define K_ 9
#define HW_ (H_ * W_)
#define HW4_ (HW_ / 4)
#define ROWF4 (W_ * C_ / 4)  // float4 pitch of one image row in featT = 4608

// ---------------------------------------------------------------------------
// Transpose features [B,C,H,W] -> [B,H,W,C], v3.  (unchanged)
// ---------------------------------------------------------------------------
__global__ __launch_bounds__(256) void transpose_kernel3(const float* __restrict__ in,
                                                         float* __restrict__ out) {
  __shared__ float tile[128][37];  // 18.9 KB
  int blk = blockIdx.x;            // ((b*H + h) << 2) | strip
  int strip = blk & 3;
  int h = (blk >> 2) & (H_ - 1);
  int b = blk >> 11;
  int w0 = strip << 7;
  int tid = threadIdx.x;

  const float4* src4 = reinterpret_cast<const float4*>(in) +
                       ((size_t)b * C_ * HW_ + (size_t)h * W_ + w0) / 4;
#pragma unroll
  for (int it = 0; it < 5; ++it) {
    int idx = it * 256 + tid;  // 0..1151 = 36 c x 32 lanes
    if (idx < C_ * 32) {
      int c = idx >> 5;
      int l = idx & 31;
      float4 v = src4[(size_t)c * HW4_ + l];
      tile[4 * l + 0][c] = v.x;
      tile[4 * l + 1][c] = v.y;
      tile[4 * l + 2][c] = v.z;
      tile[4 * l + 3][c] = v.w;
    }
  }
  __syncthreads();
  float4* dst4 = reinterpret_cast<float4*>(out + (((size_t)b * H_ + h) * W_ + w0) * C_);
#pragma unroll
  for (int it = 0; it < 5; ++it) {
    int idx = it * 256 + tid;  // float4 index 0..1151 within the strip
    if (idx < 128 * 9) {
      int px = idx / 9;
      int qq = idx - 9 * px;
      dst4[idx] = make_float4(tile[px][4 * qq + 0], tile[px][4 * qq + 1],
                              tile[px][4 * qq + 2], tile[px][4 * qq + 3]);
    }
  }
}

// ---------------------------------------------------------------------------
// v11: v10's K-split structure with the 20-float4 load window replaced by a
// rolling 2x4 double-buffer, targeting natural VGPR <= ~64.
// Fitted occupancy law over v4..v10: resident waves/SIMD ~= floor(256/VGPR)
// x ~80% — every VGPR>=88 variant sat at ~1.3-1.6 waves/SIMD regardless of
// launch bounds or LDS; every VGPR<=64 variant reached 3.2-3.9.  The only
// route to residency is shrinking live state WITHOUT spilling (clamps spill:
// v7/v9).  The 80-VGPR L[5][4] window was the consumer: now L[2][4] (32
// VGPR), issue r+1 while consuming r, fully unrolled (compile-time indices).
// Per-wave outstanding loads drop 20 -> 8; at 3-4 waves/SIMD the per-SIMD
// MLP is unchanged and waves cover each other's reduce phases (TLP replaces
// heroic ILP).  Phase-B's first load issues before reduce-A so loads stay in
// flight across it.  VALUBusy 47% @ 1.35 waves/SIMD puts the VALU floor at
// ~100us; occupancy is the only thing between 204us and that.
// ---------------------------------------------------------------------------
__global__ __launch_bounds__(192) void eval_kernel_ks(const float* __restrict__ feat,
                                                      const float* __restrict__ offx,
                                                      const float* __restrict__ offy,
                                                      float* __restrict__ out) {
  __shared__ __align__(16) float scratch[3][32 * 36];  // per-wave gather scratch; reused for merge
  __shared__ __align__(16) float4 w_lds[3][64];        // per-wave bilinear weights
  __shared__ int a_lds[3][64];                         // per-wave row0-run float4 base index
  __shared__ float F_lds[C_][64];                      // center features, channel-major (9.2 KB)

  int tid = threadIdx.x;
  int wv = tid >> 6;  // wave 0..2 -> k-set {3wv, 3wv+1, 3wv+2}
  int ln = tid & 63;

  int blk = blockIdx.x;
  int region = blk & 7;  // XCD round-robin residue -> fixed 256x256 region
  int slot = blk >> 3;   // 0..1023 within region
  int b = region >> 2;
  int qd = region & 3;
  int qy = (qd >> 1) << 8;
  int qx = (qd & 1) << 8;
  int tr = slot >> 5;  // 0..31
  int tc = slot & 31;
  if (tr & 1) tc = 31 - tc;  // serpentine: consecutive blocks share halo
  int h = qy + tr * 8 + (ln >> 3);
  int w = qx + tc * 8 + (ln & 7);
  int ph = h * W_ + w;
  int p = b * HW_ + ph;

  const float4* feat4 = reinterpret_cast<const float4*>(feat);

  // this wave's 3 candidates' offsets for my pixel
  const float* oxb = offx + (size_t)b * K_ * HW_ + ph;
  const float* oyb = offy + (size_t)b * K_ * HW_ + ph;
  float oxv[3], oyv[3];
#pragma unroll
  for (int j = 0; j < 3; ++j) {
    oxv[j] = oxb[(3 * wv + j) * HW_];
    oyv[j] = oyb[(3 * wv + j) * HW_];
  }

  // own pixel's center features -> LDS, cooperatively: wave wv loads channel
  // quads 3wv..3wv+2 of its pixel (disjoint (c,ln) cells, no races).
  {
    const float4* myF = feat4 + (size_t)p * 9;
#pragma unroll
    for (int i = 0; i < 3; ++i) {
      int ii = 3 * wv + i;
      float4 v = myF[ii];
      F_lds[4 * ii + 0][ln] = v.x;
      F_lds[4 * ii + 1][ln] = v.y;
      F_lds[4 * ii + 2][ln] = v.z;
      F_lds[4 * ii + 3][ln] = v.w;
    }
  }
  __syncthreads();

  int g = ln / 9;      // gather group 0..7 (g==7 -> lane 63, stores suppressed)
  int q = ln - 9 * g;  // channel-quad within task

  float lx = (float)w;
  float ly = (float)h;

  float M = -INFINITY, den = 0.f, axs = 0.f, ays = 0.f;

  float* myScr = scratch[wv];

#define GLOAD(Lb, T)                                \
  do {                                              \
    const float4* r0_ = feat4 + a_lds[wv][(T)];     \
    (Lb)[0] = r0_[q];                               \
    (Lb)[1] = r0_[9 + q];                           \
    (Lb)[2] = r0_[ROWF4 + q];                       \
    (Lb)[3] = r0_[ROWF4 + 9 + q];                   \
  } while (0)

#define CONSUME(Lb, T, SB, GUARD)                                            \
  do {                                                                       \
    float4 W4_ = w_lds[wv][(T)];                                             \
    float4 a4_;                                                              \
    a4_.x = W4_.x * (Lb)[0].x + W4_.y * (Lb)[1].x + W4_.z * (Lb)[2].x + W4_.w * (Lb)[3].x; \
    a4_.y = W4_.x * (Lb)[0].y + W4_.y * (Lb)[1].y + W4_.z * (Lb)[2].y + W4_.w * (Lb)[3].y; \
    a4_.z = W4_.x * (Lb)[0].z + W4_.y * (Lb)[1].z + W4_.z * (Lb)[2].z + W4_.w * (Lb)[3].z; \
    a4_.w = W4_.x * (Lb)[0].w + W4_.y * (Lb)[1].w + W4_.z * (Lb)[2].w + W4_.w * (Lb)[3].w; \
    if ((GUARD) && ln < 63) {                                                \
      *reinterpret_cast<float4*>(&myScr[(SB)*36 + 4 * q]) = a4_;             \
    }                                                                        \
  } while (0)

#pragma unroll 1
  for (int j = 0; j < 3; ++j) {
    // --- meta for my task (candidate k = 3*wv + j) ---
    float ox = oxv[j];
    float oy = oyv[j];
    float rx = fminf(fmaxf(lx + ox, 0.0f), 511.0f);
    float ry = fminf(fmaxf(ly + oy, 0.0f), 511.0f);
    float gx = (rx - 255.5f) / 255.5f;
    float gy = (ry - 255.5f) / 255.5f;
    float px = (gx + 1.0f) * 0.5f * 511.0f;
    float py = (gy + 1.0f) * 0.5f * 511.0f;
    int x0 = (int)floorf(px); x0 = (x0 > 510) ? 510 : x0;
    int y0 = (int)floorf(py); y0 = (y0 > 510) ? 510 : y0;
    float wx = px - (float)x0;
    float wy = py - (float)y0;
    w_lds[wv][ln] = make_float4((1.0f - wx) * (1.0f - wy), wx * (1.0f - wy),
                                (1.0f - wx) * wy, wx * wy);
    a_lds[wv][ln] = ((b * H_ + y0) * W_ + x0) * 9;  // float4 index of row0 run
    // no barrier: producer and consumers are the SAME wave; DS ops are
    // in-order per wave.

    float4 L[2][4];  // rolling double-buffer: 8 loads outstanding max

    // --- phase A (tasks 0..31): rolling issue/consume ---
    GLOAD(L[0], (g > 31 ? 31 : g));
#pragma unroll
    for (int r = 0; r < 5; ++r) {
      if (r < 4) {
        int ttn = 7 * (r + 1) + g;
        int tn = (ttn > 31) ? 31 : ttn;
        GLOAD(L[(r + 1) & 1], tn);
      }
      int tt = 7 * r + g;
      int t = (tt > 31) ? 31 : tt;
      CONSUME(L[r & 1], t, t, tt < 32);
    }

    // --- first phase-B load issued before reduce-A (stays in flight) ---
    {
      int tt0 = 32 + g;
      GLOAD(L[0], (tt0 > 63 ? 63 : tt0));
    }

    // --- phase-A owner reduce + softmax (lanes 0..31 own pixels 0..31) ---
    if (ln < 32) {
      float D[9] = {0.f, 0.f, 0.f, 0.f, 0.f, 0.f, 0.f, 0.f, 0.f};
      const float4* sc = reinterpret_cast<const float4*>(&myScr[ln * 36]);
#pragma unroll
      for (int q2 = 0; q2 < 9; ++q2) {
        float4 a4 = sc[q2];
        float av[4] = {a4.x, a4.y, a4.z, a4.w};
        int ga = q2 / 3;
        int f0 = 4 * (q2 % 3);
#pragma unroll
        for (int jj = 0; jj < 4; ++jj) {
          D[ga]     += fabsf(F_lds[f0 + jj][ln]      - av[jj]);
          D[3 + ga] += fabsf(F_lds[12 + f0 + jj][ln] - av[jj]);
          D[6 + ga] += fabsf(F_lds[24 + f0 + jj][ln] - av[jj]);
        }
      }
      float mn = D[0];
#pragma unroll
      for (int jj = 1; jj < 9; ++jj) mn = fminf(mn, D[jj]);
      float xk = -(mn / 12.0f) * 1000.0f;
      float nm = fmaxf(M, xk);
      float scl = expf(M - nm);
      float ek = expf(xk - nm);
      den = den * scl + ek;
      axs = axs * scl + ox * ek;
      ays = ays * scl + oy * ek;
      M = nm;
    }

    // --- phase B (tasks 32..63): rolling issue/consume.  Stores overwrite
    // scratch AFTER reduce-A has read it (in-wave DS program order). ---
#pragma unroll
    for (int r = 0; r < 5; ++r) {
      if (r < 4) {
        int ttn = 32 + 7 * (r + 1) + g;
        int tn = (ttn > 63) ? 63 : ttn;
        GLOAD(L[(r + 1) & 1], tn);
      }
      int tt = 32 + 7 * r + g;
      int t = (tt > 63) ? 63 : tt;
      CONSUME(L[r & 1], t, t - 32, tt < 64);
    }

    // --- phase-B owner reduce + softmax (lanes 32..63 own pixels 32..63) ---
    if (ln >= 32) {
      float D[9] = {0.f, 0.f, 0.f, 0.f, 0.f, 0.f, 0.f, 0.f, 0.f};
      const float4* sc = reinterpret_cast<const float4*>(&myScr[(ln - 32) * 36]);
#pragma unroll
      for (int q2 = 0; q2 < 9; ++q2) {
        float4 a4 = sc[q2];
        float av[4] = {a4.x, a4.y, a4.z, a4.w};
        int ga = q2 / 3;
        int f0 = 4 * (q2 % 3);
#pragma unroll
        for (int jj = 0; jj < 4; ++jj) {
          D[ga]     += fabsf(F_lds[f0 + jj][ln]      - av[jj]);
          D[3 + ga] += fabsf(F_lds[12 + f0 + jj][ln] - av[jj]);
          D[6 + ga] += fabsf(F_lds[24 + f0 + jj][ln] - av[jj]);
        }
      }
      float mn = D[0];
#pragma unroll
      for (int jj = 1; jj < 9; ++jj) mn = fminf(mn, D[jj]);
      float xk = -(mn / 12.0f) * 1000.0f;
      float nm = fmaxf(M, xk);
      float scl = expf(M - nm);
      float ek = expf(xk - nm);
      den = den * scl + ek;
      axs = axs * scl + ox * ek;
      ays = ays * scl + oy * ek;
      M = nm;
    }
  }
#undef GLOAD
#undef CONSUME

  // --- merge the 3 waves' partial softmax states (each lane owns pixel ln) ---
  *reinterpret_cast<float4*>(&myScr[ln * 4]) = make_float4(M, den, axs, ays);
  __syncthreads();
  if (wv == 0) {
    float4 s0 = *reinterpret_cast<const float4*>(&scratch[0][ln * 4]);
    float4 s1 = *reinterpret_cast<const float4*>(&scratch[1][ln * 4]);
    float4 s2 = *reinterpret_cast<const float4*>(&scratch[2][ln * 4]);
    float nm = fmaxf(s0.x, fmaxf(s1.x, s2.x));
    float e0 = expf(s0.x - nm);
    float e1 = expf(s1.x - nm);
    float e2 = expf(s2.x - nm);
    float dent = s0.y * e0 + s1.y * e1 + s2.y * e2;
    float ax = s0.z * e0 + s1.z * e1 + s2.z * e2;
    float ay = s0.w * e0 + s1.w * e1 + s2.w * e2;
    float resx = ax / dent;
    float resy = ay / dent;
    out[p] = fminf(fmaxf(resx + lx, 0.0f), 511.0f) - lx;
    out[B_ * HW_ + p] = fminf(fmaxf(resy + ly, 0.0f), 511.0f) - ly;
  }
}

// Fallback (no scratch): original channel-major layout, thread-per-pixel.
__global__ __launch_bounds__(256) void eval_kernel_n(const float* __restrict__ feat,
                                                     const float* __restrict__ offx,
                                                     const float* __restrict__ offy,
                                                     float* __restrict__ out) {
  int p = blockIdx.x * 256 + threadIdx.x;
  int ph = p & (HW_ - 1);
  int b = p >> 18;
  float F[C_];
  const float* fb = feat + (size_t)b * C_ * HW_ + ph;
#pragma unroll
  for (int c = 0; c < C_; ++c) F[c] = fb[(size_t)c * HW_];
  float lx = (float)(ph & (W_ - 1));
  float ly = (float)((ph >> 9) & (H_ - 1));
  const float* oxb = offx + (size_t)b * K_ * HW_ + ph;
  const float* oyb = offy + (size_t)b * K_ * HW_ + ph;
  float M = -INFINITY, den = 0.f, ax = 0.f, ay = 0.f;
#pragma unroll 1
  for (int k = 0; k < K_; ++k) {
    float ox = oxb[k * HW_];
    float oy = oyb[k * HW_];
    float rx = fminf(fmaxf(lx + ox, 0.0f), 511.0f);
    float ry = fminf(fmaxf(ly + oy, 0.0f), 511.0f);
    float gx = (rx - 255.5f) / 255.5f;
    float gy = (ry - 255.5f) / 255.5f;
    float px = (gx + 1.0f) * 0.5f * 511.0f;
    float py = (gy + 1.0f) * 0.5f * 511.0f;
    int x0 = (int)floorf(px); x0 = (x0 > 510) ? 510 : x0;
    int y0 = (int)floorf(py); y0 = (y0 > 510) ? 510 : y0;
    float wx = px - (float)x0;
    float wy = py - (float)y0;
    float w00 = (1.0f - wx) * (1.0f - wy);
    float w01 = wx * (1.0f - wy);
    float w10 = (1.0f - wx) * wy;
    float w11 = wx * wy;
    float D[9] = {0.f, 0.f, 0.f, 0.f, 0.f, 0.f, 0.f, 0.f, 0.f};
    const float* pl = feat + (size_t)b * C_ * HW_ + (size_t)y0 * W_ + x0;
#pragma unroll
    for (int c = 0; c < C_; ++c) {
      const float* q0 = pl + (size_t)c * HW_;
      float v00 = q0[0], v01 = q0[1];
      float v10 = q0[W_], v11 = q0[W_ + 1];
      float a = v00 * w00 + v01 * w01 + v10 * w10 + v11 * w11;
      int i = c % 12;
      int ga = c / 12;
      D[ga]     += fabsf(F[i]      - a);
      D[3 + ga] += fabsf(F[12 + i] - a);
      D[6 + ga] += fabsf(F[24 + i] - a);
    }
    float mn = D[0];
#pragma unroll
    for (int j = 1; j < 9; ++j) mn = fminf(mn, D[j]);
    float xk = -(mn / 12.0f) * 1000.0f;
    float nm = fmaxf(M, xk);
    float sc = expf(M - nm);
    float ek = expf(xk - nm);
    den = den * sc + ek;
    ax = ax * sc + ox * ek;
    ay = ay * sc + oy * ek;
    M = nm;
  }
  float resx = ax / den;
  float resy = ay / den;
  out[p] = fminf(fmaxf(resx + lx, 0.0f), 511.0f) - lx;
  out[B_ * HW_ + p] = fminf(fmaxf(resy + ly, 0.0f), 511.0f) - ly;
}

extern "C" void kernel_launch(void* const* d_in, const int* in_sizes, int n_in,
                              void* d_out, int out_size, void* d_ws, size_t ws_size,
                              hipStream_t stream) {
  const float* features = (const float*)d_in[0];
  const float* offset_x = (const float*)d_in[1];
  const float* offset_y = (const float*)d_in[2];
  float* out = (float*)d_out;

  const int npix = B_ * HW_;  // 524288
  const size_t need = (size_t)npix * C_ * sizeof(float);  // 75.5 MB

  if (ws_size >= need) {
    float* featT = (float*)d_ws;
    transpose_kernel3<<<B_ * H_ * 4, 256, 0, stream>>>(features, featT);
    eval_kernel_ks<<<npix / 64, 192, 0, stream>>>(featT, offset_x, offset_y, out);
  } else {
    eval_kernel_n<<<npix / 256, 256, 0, stream>>>(features, offset_x, offset_y, out);
  }
}